// Round 1
// baseline (131.268 us; speedup 1.0000x reference)
//
#include <hip/hip_runtime.h>
#include <hip/hip_bf16.h>

#define SEQ 4096
#define DM  512
#define DK  64
#define CHUNK 1024
#define NCHUNK (SEQ / CHUNK)

typedef short bf16x8 __attribute__((ext_vector_type(8)));
typedef float f32x4  __attribute__((ext_vector_type(4)));

static __device__ __forceinline__ unsigned short f2bf(float f) {
    unsigned int u = __builtin_bit_cast(unsigned int, f);
    unsigned int r = u + 0x7FFFu + ((u >> 16) & 1u);
    return (unsigned short)(r >> 16);
}

static __device__ __forceinline__ bf16x8 load8_cvt(const float* __restrict__ p) {
    f32x4 a = *(const f32x4*)p;
    f32x4 b = *(const f32x4*)(p + 4);
    bf16x8 r;
    r[0] = (short)f2bf(a[0]); r[1] = (short)f2bf(a[1]);
    r[2] = (short)f2bf(a[2]); r[3] = (short)f2bf(a[3]);
    r[4] = (short)f2bf(b[0]); r[5] = (short)f2bf(b[1]);
    r[6] = (short)f2bf(b[2]); r[7] = (short)f2bf(b[3]);
    return r;
}

// ---------------------------------------------------------------------------
// Kernel 1: QKV projection.  blockIdx.y: 0=Q, 1=K, 2=V(transposed output)
//   Q,K: out[q][d] bf16 row-major [SEQ][64]
//   V:   outT[d][q] bf16 [64][SEQ]   (V^T = Wv * E^T)
// ---------------------------------------------------------------------------
__global__ __launch_bounds__(256) void proj_kernel(
    const float* __restrict__ E,
    const float* __restrict__ Wq, const float* __restrict__ bq,
    const float* __restrict__ Wk, const float* __restrict__ bk,
    const float* __restrict__ Wv, const float* __restrict__ bv,
    unsigned short* __restrict__ Qb, unsigned short* __restrict__ Kb,
    unsigned short* __restrict__ VbT)
{
    const int which = blockIdx.y;
    const int bx = blockIdx.x;
    const int tid = (int)threadIdx.x;
    const int w  = tid >> 6;
    const int l  = tid & 63;
    const int lo = l & 15;
    const int hi = l >> 4;

    f32x4 acc[4] = {};

    if (which < 2) {
        const float* W    = (which == 0) ? Wq : Wk;
        const float* bias = (which == 0) ? bq : bk;
        unsigned short* out = (which == 0) ? Qb : Kb;
        const int r0 = bx * 64 + w * 16;
        for (int k0 = 0; k0 < DM; k0 += 32) {
            bf16x8 a = load8_cvt(&E[(size_t)(r0 + lo) * DM + k0 + hi * 8]);
#pragma unroll
            for (int ct = 0; ct < 4; ++ct) {
                bf16x8 b = load8_cvt(&W[(size_t)(lo + 16 * ct) * DM + k0 + hi * 8]);
                acc[ct] = __builtin_amdgcn_mfma_f32_16x16x32_bf16(a, b, acc[ct], 0, 0, 0);
            }
        }
#pragma unroll
        for (int ct = 0; ct < 4; ++ct) {
            float bcol = bias[lo + 16 * ct];
#pragma unroll
            for (int r = 0; r < 4; ++r) {
                int q = r0 + hi * 4 + r;
                out[(size_t)q * 64 + lo + 16 * ct] = f2bf(acc[ct][r] + bcol);
            }
        }
    } else {
        const int n0 = bx * 64;   // seq columns
        const int d0 = w * 16;    // d rows for this wave
        for (int k0 = 0; k0 < DM; k0 += 32) {
            bf16x8 a = load8_cvt(&Wv[(size_t)(d0 + lo) * DM + k0 + hi * 8]);
#pragma unroll
            for (int ct = 0; ct < 4; ++ct) {
                bf16x8 b = load8_cvt(&E[(size_t)(n0 + lo + 16 * ct) * DM + k0 + hi * 8]);
                acc[ct] = __builtin_amdgcn_mfma_f32_16x16x32_bf16(a, b, acc[ct], 0, 0, 0);
            }
        }
#pragma unroll
        for (int ct = 0; ct < 4; ++ct) {
#pragma unroll
            for (int r = 0; r < 4; ++r) {
                int d = d0 + hi * 4 + r;
                VbT[(size_t)d * SEQ + n0 + lo + 16 * ct] = f2bf(acc[ct][r] + bv[d]);
            }
        }
    }
}

// ---------------------------------------------------------------------------
// Kernel 2: causal flash attention, split-KV.
//   grid (SEQ/16, NCHUNK), 1 wave per block, 16 q-rows per block.
//   Writes unnormalized partial O + (m, l) per (row, chunk).
// ---------------------------------------------------------------------------
#define L2E 1.4426950408889634f

__global__ __launch_bounds__(64) void attn_kernel(
    const unsigned short* __restrict__ Qb,
    const unsigned short* __restrict__ Kb,
    const unsigned short* __restrict__ VbT,
    float* __restrict__ Opart, float* __restrict__ ml)
{
    const int qi  = blockIdx.x;
    const int c   = blockIdx.y;
    const int q0  = qi * 16;
    const int kb0 = c * CHUNK;
    if (kb0 > q0) return;   // fully masked chunk

    const int l  = (int)threadIdx.x;
    const int lo = l & 15;
    const int hi = l >> 4;

    __shared__ unsigned short Pl[16][80];   // padded: row stride 160B

    bf16x8 qf0 = *(const bf16x8*)&Qb[(size_t)(q0 + lo) * 64 + hi * 8];
    bf16x8 qf1 = *(const bf16x8*)&Qb[(size_t)(q0 + lo) * 64 + 32 + hi * 8];

    float m[4], lsum[4];
    f32x4 o[4] = {};
#pragma unroll
    for (int r = 0; r < 4; ++r) { m[r] = -1e30f; lsum[r] = 0.f; }

    const int kend = min(kb0 + CHUNK, q0 + 16);
    for (int kb = kb0; kb < kend; kb += 64) {
        // ---- QK^T (16 q x 64 k) ----
        f32x4 s[4] = {};
#pragma unroll
        for (int ct = 0; ct < 4; ++ct) {
            bf16x8 kf0 = *(const bf16x8*)&Kb[(size_t)(kb + lo + 16 * ct) * 64 + hi * 8];
            bf16x8 kf1 = *(const bf16x8*)&Kb[(size_t)(kb + lo + 16 * ct) * 64 + 32 + hi * 8];
            s[ct] = __builtin_amdgcn_mfma_f32_16x16x32_bf16(qf0, kf0, s[ct], 0, 0, 0);
            s[ct] = __builtin_amdgcn_mfma_f32_16x16x32_bf16(qf1, kf1, s[ct], 0, 0, 0);
        }
        // ---- scale + causal mask + row max ----
        float mt[4] = { -1e30f, -1e30f, -1e30f, -1e30f };
#pragma unroll
        for (int ct = 0; ct < 4; ++ct) {
            int key = kb + lo + 16 * ct;
#pragma unroll
            for (int r = 0; r < 4; ++r) {
                float v = s[ct][r] * 0.125f;
                int q = q0 + hi * 4 + r;
                if (key > q) v = -3.0e38f;
                s[ct][r] = v;
                mt[r] = fmaxf(mt[r], v);
            }
        }
#pragma unroll
        for (int mask = 1; mask < 16; mask <<= 1)
#pragma unroll
            for (int r = 0; r < 4; ++r) mt[r] = fmaxf(mt[r], __shfl_xor(mt[r], mask));
        // ---- online softmax update ----
        float alpha[4], mn[4];
#pragma unroll
        for (int r = 0; r < 4; ++r) {
            mn[r] = fmaxf(m[r], mt[r]);
            alpha[r] = exp2f((m[r] - mn[r]) * L2E);
            m[r] = mn[r];
        }
        float ps[4] = { 0.f, 0.f, 0.f, 0.f };
#pragma unroll
        for (int ct = 0; ct < 4; ++ct) {
#pragma unroll
            for (int r = 0; r < 4; ++r) {
                float p = exp2f((s[ct][r] - mn[r]) * L2E);
                s[ct][r] = p;
                ps[r] += p;
            }
        }
#pragma unroll
        for (int mask = 1; mask < 16; mask <<= 1)
#pragma unroll
            for (int r = 0; r < 4; ++r) ps[r] += __shfl_xor(ps[r], mask);
#pragma unroll
        for (int r = 0; r < 4; ++r) lsum[r] = lsum[r] * alpha[r] + ps[r];
#pragma unroll
        for (int dt = 0; dt < 4; ++dt)
#pragma unroll
            for (int r = 0; r < 4; ++r) o[dt][r] *= alpha[r];
        // ---- P -> bf16 -> LDS (re-fragment for PV) ----
#pragma unroll
        for (int ct = 0; ct < 4; ++ct)
#pragma unroll
            for (int r = 0; r < 4; ++r)
                Pl[hi * 4 + r][lo + 16 * ct] = f2bf(s[ct][r]);
        __syncthreads();
        bf16x8 pa0 = *(const bf16x8*)&Pl[lo][hi * 8];
        bf16x8 pa1 = *(const bf16x8*)&Pl[lo][32 + hi * 8];
        // ---- PV ----
#pragma unroll
        for (int dt = 0; dt < 4; ++dt) {
            bf16x8 v0 = *(const bf16x8*)&VbT[(size_t)(lo + 16 * dt) * SEQ + kb + hi * 8];
            bf16x8 v1 = *(const bf16x8*)&VbT[(size_t)(lo + 16 * dt) * SEQ + kb + 32 + hi * 8];
            o[dt] = __builtin_amdgcn_mfma_f32_16x16x32_bf16(pa0, v0, o[dt], 0, 0, 0);
            o[dt] = __builtin_amdgcn_mfma_f32_16x16x32_bf16(pa1, v1, o[dt], 0, 0, 0);
        }
        __syncthreads();   // protect Pl before next iteration
    }

    // ---- write partials ----
#pragma unroll
    for (int dt = 0; dt < 4; ++dt)
#pragma unroll
        for (int r = 0; r < 4; ++r) {
            int q = q0 + hi * 4 + r;
            Opart[((size_t)q * NCHUNK + c) * 64 + lo + 16 * dt] = o[dt][r];
        }
    if (lo == 0) {
#pragma unroll
        for (int r = 0; r < 4; ++r) {
            int q = q0 + hi * 4 + r;
            ml[((size_t)q * NCHUNK + c) * 2 + 0] = m[r];
            ml[((size_t)q * NCHUNK + c) * 2 + 1] = lsum[r];
        }
    }
}

// ---------------------------------------------------------------------------
// Kernel 3: merge split-KV partials. One thread per output element.
// ---------------------------------------------------------------------------
__global__ __launch_bounds__(256) void merge_kernel(
    const float* __restrict__ Opart, const float* __restrict__ ml,
    float* __restrict__ out)
{
    int gid = (int)(blockIdx.x * 256 + threadIdx.x);
    int q = gid >> 6;
    int d = gid & 63;
    int nc = (q >> 10) + 1;   // chunks 0..q/CHUNK are active
    float M = -1e30f;
    for (int cc = 0; cc < nc; ++cc)
        M = fmaxf(M, ml[((size_t)q * NCHUNK + cc) * 2]);
    float L = 0.f, acc = 0.f;
    for (int cc = 0; cc < nc; ++cc) {
        float e = exp2f((ml[((size_t)q * NCHUNK + cc) * 2] - M) * L2E);
        L   += e * ml[((size_t)q * NCHUNK + cc) * 2 + 1];
        acc += e * Opart[((size_t)q * NCHUNK + cc) * 64 + d];
    }
    out[(size_t)q * 64 + d] = acc / L;
}

// ---------------------------------------------------------------------------
extern "C" void kernel_launch(void* const* d_in, const int* in_sizes, int n_in,
                              void* d_out, int out_size, void* d_ws, size_t ws_size,
                              hipStream_t stream) {
    const float* E  = (const float*)d_in[0];
    const float* Wq = (const float*)d_in[1];
    const float* bq = (const float*)d_in[2];
    const float* Wk = (const float*)d_in[3];
    const float* bk = (const float*)d_in[4];
    const float* Wv = (const float*)d_in[5];
    const float* bv = (const float*)d_in[6];
    float* out = (float*)d_out;

    char* ws = (char*)d_ws;
    unsigned short* Qb  = (unsigned short*)(ws);                    // 512 KB
    unsigned short* Kb  = (unsigned short*)(ws + (512u << 10));     // 512 KB
    unsigned short* VbT = (unsigned short*)(ws + (1024u << 10));    // 512 KB
    float* Opart = (float*)(ws + (1536u << 10));                    // 4 MB
    float* mlbuf = (float*)(ws + (1536u << 10) + (4096u << 10));    // 128 KB

    hipLaunchKernelGGL(proj_kernel, dim3(64, 3), dim3(256), 0, stream,
                       E, Wq, bq, Wk, bk, Wv, bv, Qb, Kb, VbT);
    hipLaunchKernelGGL(attn_kernel, dim3(SEQ / 16, NCHUNK), dim3(64), 0, stream,
                       Qb, Kb, VbT, Opart, mlbuf);
    hipLaunchKernelGGL(merge_kernel, dim3(SEQ * 64 / 256), dim3(256), 0, stream,
                       Opart, mlbuf, out);
}

// Round 2
// 120.110 us; speedup vs baseline: 1.0929x; 1.0929x over previous
//
#include <hip/hip_runtime.h>
#include <hip/hip_bf16.h>

#define SEQ 4096
#define DM  512
#define DK  64
#define CHUNK 1024
#define NCHUNK (SEQ / CHUNK)

typedef short bf16x8 __attribute__((ext_vector_type(8)));
typedef float f32x4  __attribute__((ext_vector_type(4)));

static __device__ __forceinline__ unsigned short f2bf(float f) {
    unsigned int u = __builtin_bit_cast(unsigned int, f);
    unsigned int r = u + 0x7FFFu + ((u >> 16) & 1u);
    return (unsigned short)(r >> 16);
}

static __device__ __forceinline__ bf16x8 load8_cvt(const float* __restrict__ p) {
    f32x4 a = *(const f32x4*)p;
    f32x4 b = *(const f32x4*)(p + 4);
    bf16x8 r;
    r[0] = (short)f2bf(a[0]); r[1] = (short)f2bf(a[1]);
    r[2] = (short)f2bf(a[2]); r[3] = (short)f2bf(a[3]);
    r[4] = (short)f2bf(b[0]); r[5] = (short)f2bf(b[1]);
    r[6] = (short)f2bf(b[2]); r[7] = (short)f2bf(b[3]);
    return r;
}

// ---------------------------------------------------------------------------
// Kernel 1: QKV projection. One wave per block; grid (SEQ/16, 3).
//   blockIdx.y: 0=Q, 1=K, 2=V(transposed output)
//   Q,K: out[q][d] bf16 row-major [SEQ][64]
//   V:   outT[d][q] bf16 [64][SEQ]   (V^T = Wv * E^T)
// ---------------------------------------------------------------------------
__global__ __launch_bounds__(64) void proj_kernel(
    const float* __restrict__ E,
    const float* __restrict__ Wq, const float* __restrict__ bq,
    const float* __restrict__ Wk, const float* __restrict__ bk,
    const float* __restrict__ Wv, const float* __restrict__ bv,
    unsigned short* __restrict__ Qb, unsigned short* __restrict__ Kb,
    unsigned short* __restrict__ VbT)
{
    const int which = blockIdx.y;
    const int bx = blockIdx.x;            // 0..255, 16 seq rows each
    const int l  = (int)threadIdx.x;
    const int lo = l & 15;
    const int hi = l >> 4;

    f32x4 acc[4] = {};

    if (which < 2) {
        const float* W    = (which == 0) ? Wq : Wk;
        const float* bias = (which == 0) ? bq : bk;
        unsigned short* out = (which == 0) ? Qb : Kb;
        const int r0 = bx * 16;
        for (int k0 = 0; k0 < DM; k0 += 32) {
            bf16x8 a = load8_cvt(&E[(size_t)(r0 + lo) * DM + k0 + hi * 8]);
#pragma unroll
            for (int ct = 0; ct < 4; ++ct) {
                bf16x8 b = load8_cvt(&W[(size_t)(lo + 16 * ct) * DM + k0 + hi * 8]);
                acc[ct] = __builtin_amdgcn_mfma_f32_16x16x32_bf16(a, b, acc[ct], 0, 0, 0);
            }
        }
#pragma unroll
        for (int ct = 0; ct < 4; ++ct) {
            float bcol = bias[lo + 16 * ct];
#pragma unroll
            for (int r = 0; r < 4; ++r) {
                int q = r0 + hi * 4 + r;
                out[(size_t)q * 64 + lo + 16 * ct] = f2bf(acc[ct][r] + bcol);
            }
        }
    } else {
        const int n0 = bx * 16;           // 16 seq columns of V^T
        for (int k0 = 0; k0 < DM; k0 += 32) {
            bf16x8 b = load8_cvt(&E[(size_t)(n0 + lo) * DM + k0 + hi * 8]);
#pragma unroll
            for (int ct = 0; ct < 4; ++ct) {
                bf16x8 a = load8_cvt(&Wv[(size_t)(lo + 16 * ct) * DM + k0 + hi * 8]);
                acc[ct] = __builtin_amdgcn_mfma_f32_16x16x32_bf16(a, b, acc[ct], 0, 0, 0);
            }
        }
#pragma unroll
        for (int ct = 0; ct < 4; ++ct) {
#pragma unroll
            for (int r = 0; r < 4; ++r) {
                int d = 16 * ct + hi * 4 + r;
                VbT[(size_t)d * SEQ + n0 + lo] = f2bf(acc[ct][r] + bv[d]);
            }
        }
    }
}

// ---------------------------------------------------------------------------
// Kernel 2: causal flash attention, split-KV, 4 waves per block.
//   grid (SEQ/16, NCHUNK), block 256. Wave w takes k-steps kb0+w*64+i*256
//   (interleaved => balanced near the diagonal; softmax order-independent).
//   Per-wave private LDS P tile, no intra-loop barrier. End: in-LDS LSE
//   combine of the 4 wave partials -> Opart, ml (per chunk).
// ---------------------------------------------------------------------------
#define L2E 1.4426950408889634f

__global__ __launch_bounds__(256) void attn_kernel(
    const unsigned short* __restrict__ Qb,
    const unsigned short* __restrict__ Kb,
    const unsigned short* __restrict__ VbT,
    float* __restrict__ Opart, float* __restrict__ ml)
{
    const int qi  = blockIdx.x;
    const int c   = blockIdx.y;
    const int q0  = qi * 16;
    const int kb0 = c * CHUNK;
    if (kb0 > q0) return;   // fully masked chunk

    const int tid = (int)threadIdx.x;
    const int w   = tid >> 6;
    const int l   = tid & 63;
    const int lo  = l & 15;
    const int hi  = l >> 4;

    __shared__ unsigned short Pl[4][16][80];   // per-wave P tile (padded)
    __shared__ float Osh[4][16][64];
    __shared__ float msh[4][16];
    __shared__ float lsh[4][16];

    bf16x8 qf0 = *(const bf16x8*)&Qb[(size_t)(q0 + lo) * 64 + hi * 8];
    bf16x8 qf1 = *(const bf16x8*)&Qb[(size_t)(q0 + lo) * 64 + 32 + hi * 8];

    float m[4], lsum[4];
    f32x4 o[4] = {};
#pragma unroll
    for (int r = 0; r < 4; ++r) { m[r] = -1e30f; lsum[r] = 0.f; }

    const int kend = min(kb0 + CHUNK, q0 + 16);
    for (int kb = kb0 + w * 64; kb < kend; kb += 256) {
        // ---- QK^T (16 q x 64 k) ----
        f32x4 s[4] = {};
#pragma unroll
        for (int ct = 0; ct < 4; ++ct) {
            bf16x8 kf0 = *(const bf16x8*)&Kb[(size_t)(kb + lo + 16 * ct) * 64 + hi * 8];
            bf16x8 kf1 = *(const bf16x8*)&Kb[(size_t)(kb + lo + 16 * ct) * 64 + 32 + hi * 8];
            s[ct] = __builtin_amdgcn_mfma_f32_16x16x32_bf16(qf0, kf0, s[ct], 0, 0, 0);
            s[ct] = __builtin_amdgcn_mfma_f32_16x16x32_bf16(qf1, kf1, s[ct], 0, 0, 0);
        }
        // ---- scale + causal mask + row max ----
        float mt[4] = { -1e30f, -1e30f, -1e30f, -1e30f };
#pragma unroll
        for (int ct = 0; ct < 4; ++ct) {
            int key = kb + lo + 16 * ct;
#pragma unroll
            for (int r = 0; r < 4; ++r) {
                float v = s[ct][r] * 0.125f;
                int q = q0 + hi * 4 + r;
                if (key > q) v = -3.0e38f;
                s[ct][r] = v;
                mt[r] = fmaxf(mt[r], v);
            }
        }
#pragma unroll
        for (int mask = 1; mask < 16; mask <<= 1)
#pragma unroll
            for (int r = 0; r < 4; ++r) mt[r] = fmaxf(mt[r], __shfl_xor(mt[r], mask));
        // ---- online softmax update ----
        float alpha[4], mn[4];
#pragma unroll
        for (int r = 0; r < 4; ++r) {
            mn[r] = fmaxf(m[r], mt[r]);
            alpha[r] = exp2f((m[r] - mn[r]) * L2E);
            m[r] = mn[r];
        }
        float ps[4] = { 0.f, 0.f, 0.f, 0.f };
#pragma unroll
        for (int ct = 0; ct < 4; ++ct) {
#pragma unroll
            for (int r = 0; r < 4; ++r) {
                float p = exp2f((s[ct][r] - mn[r]) * L2E);
                s[ct][r] = p;
                ps[r] += p;
            }
        }
#pragma unroll
        for (int mask = 1; mask < 16; mask <<= 1)
#pragma unroll
            for (int r = 0; r < 4; ++r) ps[r] += __shfl_xor(ps[r], mask);
#pragma unroll
        for (int r = 0; r < 4; ++r) lsum[r] = lsum[r] * alpha[r] + ps[r];
#pragma unroll
        for (int dt = 0; dt < 4; ++dt)
#pragma unroll
            for (int r = 0; r < 4; ++r) o[dt][r] *= alpha[r];
        // ---- P -> bf16 -> per-wave LDS (re-fragment for PV) ----
#pragma unroll
        for (int ct = 0; ct < 4; ++ct)
#pragma unroll
            for (int r = 0; r < 4; ++r)
                Pl[w][hi * 4 + r][lo + 16 * ct] = f2bf(s[ct][r]);
        asm volatile("" ::: "memory");   // keep write->read order; LDS is in-order per wave
        bf16x8 pa0 = *(const bf16x8*)&Pl[w][lo][hi * 8];
        bf16x8 pa1 = *(const bf16x8*)&Pl[w][lo][32 + hi * 8];
        // ---- PV ----
#pragma unroll
        for (int dt = 0; dt < 4; ++dt) {
            bf16x8 v0 = *(const bf16x8*)&VbT[(size_t)(lo + 16 * dt) * SEQ + kb + hi * 8];
            bf16x8 v1 = *(const bf16x8*)&VbT[(size_t)(lo + 16 * dt) * SEQ + kb + 32 + hi * 8];
            o[dt] = __builtin_amdgcn_mfma_f32_16x16x32_bf16(pa0, v0, o[dt], 0, 0, 0);
            o[dt] = __builtin_amdgcn_mfma_f32_16x16x32_bf16(pa1, v1, o[dt], 0, 0, 0);
        }
        asm volatile("" ::: "memory");   // Pl reused next iteration
    }

    // ---- stage wave partials in LDS ----
#pragma unroll
    for (int dt = 0; dt < 4; ++dt)
#pragma unroll
        for (int r = 0; r < 4; ++r)
            Osh[w][hi * 4 + r][lo + 16 * dt] = o[dt][r];
    if (lo == 0) {
#pragma unroll
        for (int r = 0; r < 4; ++r) {
            msh[w][hi * 4 + r] = m[r];
            lsh[w][hi * 4 + r] = lsum[r];
        }
    }
    __syncthreads();

    // ---- combine the 4 wave partials (LSE) ----
    {
        int q  = tid >> 4;          // 0..15
        int d0 = (tid & 15) * 4;    // 4 d-elements per thread
        float M = fmaxf(fmaxf(msh[0][q], msh[1][q]), fmaxf(msh[2][q], msh[3][q]));
        float L = 0.f;
        f32x4 acc = {};
#pragma unroll
        for (int ww = 0; ww < 4; ++ww) {
            float e = exp2f((msh[ww][q] - M) * L2E);
            L += e * lsh[ww][q];
#pragma unroll
            for (int j = 0; j < 4; ++j)
                acc[j] += e * Osh[ww][q][d0 + j];
        }
        float* op = &Opart[((size_t)(q0 + q) * NCHUNK + c) * 64 + d0];
        *(f32x4*)op = acc;
        if ((tid & 15) == 0) {
            ml[((size_t)(q0 + q) * NCHUNK + c) * 2 + 0] = M;
            ml[((size_t)(q0 + q) * NCHUNK + c) * 2 + 1] = L;
        }
    }
}

// ---------------------------------------------------------------------------
// Kernel 3: merge split-KV partials. One thread per output element.
// ---------------------------------------------------------------------------
__global__ __launch_bounds__(256) void merge_kernel(
    const float* __restrict__ Opart, const float* __restrict__ ml,
    float* __restrict__ out)
{
    int gid = (int)(blockIdx.x * 256 + threadIdx.x);
    int q = gid >> 6;
    int d = gid & 63;
    int nc = (q >> 10) + 1;   // chunks 0..q/CHUNK are active
    float M = -1e30f;
    for (int cc = 0; cc < nc; ++cc)
        M = fmaxf(M, ml[((size_t)q * NCHUNK + cc) * 2]);
    float L = 0.f, acc = 0.f;
    for (int cc = 0; cc < nc; ++cc) {
        float e = exp2f((ml[((size_t)q * NCHUNK + cc) * 2] - M) * L2E);
        L   += e * ml[((size_t)q * NCHUNK + cc) * 2 + 1];
        acc += e * Opart[((size_t)q * NCHUNK + cc) * 64 + d];
    }
    out[(size_t)q * 64 + d] = acc / L;
}

// ---------------------------------------------------------------------------
extern "C" void kernel_launch(void* const* d_in, const int* in_sizes, int n_in,
                              void* d_out, int out_size, void* d_ws, size_t ws_size,
                              hipStream_t stream) {
    const float* E  = (const float*)d_in[0];
    const float* Wq = (const float*)d_in[1];
    const float* bq = (const float*)d_in[2];
    const float* Wk = (const float*)d_in[3];
    const float* bk = (const float*)d_in[4];
    const float* Wv = (const float*)d_in[5];
    const float* bv = (const float*)d_in[6];
    float* out = (float*)d_out;

    char* ws = (char*)d_ws;
    unsigned short* Qb  = (unsigned short*)(ws);                    // 512 KB
    unsigned short* Kb  = (unsigned short*)(ws + (512u << 10));     // 512 KB
    unsigned short* VbT = (unsigned short*)(ws + (1024u << 10));    // 512 KB
    float* Opart = (float*)(ws + (1536u << 10));                    // 4 MB
    float* mlbuf = (float*)(ws + (1536u << 10) + (4096u << 10));    // 128 KB

    hipLaunchKernelGGL(proj_kernel, dim3(SEQ / 16, 3), dim3(64), 0, stream,
                       E, Wq, bq, Wk, bk, Wv, bv, Qb, Kb, VbT);
    hipLaunchKernelGGL(attn_kernel, dim3(SEQ / 16, NCHUNK), dim3(256), 0, stream,
                       Qb, Kb, VbT, Opart, mlbuf);
    hipLaunchKernelGGL(merge_kernel, dim3(SEQ * 64 / 256), dim3(256), 0, stream,
                       Opart, mlbuf, out);
}

// Round 3
// 119.634 us; speedup vs baseline: 1.0972x; 1.0040x over previous
//
#include <hip/hip_runtime.h>
#include <hip/hip_bf16.h>

#define SEQ 4096
#define DM  512

typedef short bf16x8 __attribute__((ext_vector_type(8)));
typedef short s16x4  __attribute__((ext_vector_type(4)));
typedef float f32x4  __attribute__((ext_vector_type(4)));

#define L2E 1.4426950408889634f

static __device__ __forceinline__ unsigned short f2bf(float f) {
    unsigned int u = __builtin_bit_cast(unsigned int, f);
    unsigned int r = u + 0x7FFFu + ((u >> 16) & 1u);
    return (unsigned short)(r >> 16);
}

static __device__ __forceinline__ bf16x8 load8_cvt(const float* __restrict__ p) {
    f32x4 a = *(const f32x4*)p;
    f32x4 b = *(const f32x4*)(p + 4);
    bf16x8 r;
    r[0] = (short)f2bf(a[0]); r[1] = (short)f2bf(a[1]);
    r[2] = (short)f2bf(a[2]); r[3] = (short)f2bf(a[3]);
    r[4] = (short)f2bf(b[0]); r[5] = (short)f2bf(b[1]);
    r[6] = (short)f2bf(b[2]); r[7] = (short)f2bf(b[3]);
    return r;
}

// ---------------------------------------------------------------------------
// Kernel 1: QKV projection, split-K across 4 waves + LDS f32 reduce.
//   grid (SEQ/16, 3), block 256.  blockIdx.y: 0=Q, 1=K, 2=V(transposed out)
//   Q,K: [SEQ][64] bf16 row-major;  V: VbT[d][n] = V^T, [64][SEQ] bf16.
// ---------------------------------------------------------------------------
__global__ __launch_bounds__(256) void proj_kernel(
    const float* __restrict__ E,
    const float* __restrict__ Wq, const float* __restrict__ bq,
    const float* __restrict__ Wk, const float* __restrict__ bk,
    const float* __restrict__ Wv, const float* __restrict__ bv,
    unsigned short* __restrict__ Qb, unsigned short* __restrict__ Kb,
    unsigned short* __restrict__ VbT)
{
    const int which = blockIdx.y;
    const int bx  = blockIdx.x;           // 16 seq rows (Q/K) or 16 seq cols (V^T)
    const int tid = (int)threadIdx.x;
    const int w   = tid >> 6;             // wave 0..3: K-chunk w*128..w*128+127
    const int l   = tid & 63;
    const int lo  = l & 15;
    const int hi  = l >> 4;

    __shared__ float Acc[5120];           // Q/K: [4][16][68]; V: [4][64][20]

    f32x4 acc[4] = {};

    if (which < 2) {
        const float* W    = (which == 0) ? Wq : Wk;
        const float* bias = (which == 0) ? bq : bk;
        unsigned short* out = (which == 0) ? Qb : Kb;
        const int r0 = bx * 16;
#pragma unroll
        for (int kk = 0; kk < 4; ++kk) {
            const int k0 = w * 128 + kk * 32;
            bf16x8 a = load8_cvt(&E[(size_t)(r0 + lo) * DM + k0 + hi * 8]);
#pragma unroll
            for (int ct = 0; ct < 4; ++ct) {
                bf16x8 b = load8_cvt(&W[(size_t)(lo + 16 * ct) * DM + k0 + hi * 8]);
                acc[ct] = __builtin_amdgcn_mfma_f32_16x16x32_bf16(a, b, acc[ct], 0, 0, 0);
            }
        }
#pragma unroll
        for (int ct = 0; ct < 4; ++ct)
#pragma unroll
            for (int r = 0; r < 4; ++r)
                Acc[(w * 16 + hi * 4 + r) * 68 + lo + 16 * ct] = acc[ct][r];
        __syncthreads();
        {   // reduce: 16 rows x 16 col-groups of 4
            const int row = tid >> 4;
            const int c0  = (tid & 15) * 4;
            f32x4 sum = {};
#pragma unroll
            for (int ww = 0; ww < 4; ++ww)
                sum += *(const f32x4*)&Acc[(ww * 16 + row) * 68 + c0];
            s16x4 o4;
#pragma unroll
            for (int j = 0; j < 4; ++j)
                o4[j] = (short)f2bf(sum[j] + bias[c0 + j]);
            *(s16x4*)&out[(size_t)(r0 + row) * 64 + c0] = o4;
        }
    } else {
        const int n0 = bx * 16;           // 16 seq columns of V^T
#pragma unroll
        for (int kk = 0; kk < 4; ++kk) {
            const int k0 = w * 128 + kk * 32;
            bf16x8 b = load8_cvt(&E[(size_t)(n0 + lo) * DM + k0 + hi * 8]);
#pragma unroll
            for (int ct = 0; ct < 4; ++ct) {
                bf16x8 a = load8_cvt(&Wv[(size_t)(lo + 16 * ct) * DM + k0 + hi * 8]);
                acc[ct] = __builtin_amdgcn_mfma_f32_16x16x32_bf16(a, b, acc[ct], 0, 0, 0);
            }
        }
#pragma unroll
        for (int ct = 0; ct < 4; ++ct)
#pragma unroll
            for (int r = 0; r < 4; ++r)
                Acc[(w * 64 + 16 * ct + hi * 4 + r) * 20 + lo] = acc[ct][r];
        __syncthreads();
        {   // reduce: 64 d-rows x 4 n-groups of 4
            const int d  = tid >> 2;
            const int n4 = (tid & 3) * 4;
            f32x4 sum = {};
#pragma unroll
            for (int ww = 0; ww < 4; ++ww)
                sum += *(const f32x4*)&Acc[(ww * 64 + d) * 20 + n4];
            const float bd = bv[d];
            s16x4 o4;
#pragma unroll
            for (int j = 0; j < 4; ++j)
                o4[j] = (short)f2bf(sum[j] + bd);
            *(s16x4*)&VbT[(size_t)d * SEQ + n0 + n4] = o4;
        }
    }
}

// ---------------------------------------------------------------------------
// Kernel 2: causal flash attention, single pass, 8 waves per block.
//   grid (SEQ/16), block 512. Wave w takes k-blocks w, w+8, ... over the
//   full causal range [0, q0+16). Per-wave private LDS P tile, no intra-loop
//   barrier (divergent trip counts). End: in-LDS LSE combine of the 8 wave
//   partials -> final output, normalized. No split-KV buffers, no merge.
// ---------------------------------------------------------------------------
__global__ __launch_bounds__(512) void attn_kernel(
    const unsigned short* __restrict__ Qb,
    const unsigned short* __restrict__ Kb,
    const unsigned short* __restrict__ VbT,
    float* __restrict__ out)
{
    const int q0  = blockIdx.x * 16;
    const int tid = (int)threadIdx.x;
    const int w   = tid >> 6;
    const int l   = tid & 63;
    const int lo  = l & 15;
    const int hi  = l >> 4;

    __shared__ unsigned short Pl[8][16][80];   // per-wave P tile (padded)
    __shared__ float Osh[8][16][64];
    __shared__ float msh[8][16];
    __shared__ float lsh[8][16];

    bf16x8 qf0 = *(const bf16x8*)&Qb[(size_t)(q0 + lo) * 64 + hi * 8];
    bf16x8 qf1 = *(const bf16x8*)&Qb[(size_t)(q0 + lo) * 64 + 32 + hi * 8];

    float m[4], lsum[4];
    f32x4 o[4] = {};
#pragma unroll
    for (int r = 0; r < 4; ++r) { m[r] = -1e30f; lsum[r] = 0.f; }

    const int kend = q0 + 16;
    for (int kb = w * 64; kb < kend; kb += 512) {
        // ---- QK^T (16 q x 64 k) ----
        f32x4 s[4] = {};
#pragma unroll
        for (int ct = 0; ct < 4; ++ct) {
            bf16x8 kf0 = *(const bf16x8*)&Kb[(size_t)(kb + lo + 16 * ct) * 64 + hi * 8];
            bf16x8 kf1 = *(const bf16x8*)&Kb[(size_t)(kb + lo + 16 * ct) * 64 + 32 + hi * 8];
            s[ct] = __builtin_amdgcn_mfma_f32_16x16x32_bf16(qf0, kf0, s[ct], 0, 0, 0);
            s[ct] = __builtin_amdgcn_mfma_f32_16x16x32_bf16(qf1, kf1, s[ct], 0, 0, 0);
        }
        // ---- scale + causal mask + row max ----
        float mt[4] = { -1e30f, -1e30f, -1e30f, -1e30f };
#pragma unroll
        for (int ct = 0; ct < 4; ++ct) {
            int key = kb + lo + 16 * ct;
#pragma unroll
            for (int r = 0; r < 4; ++r) {
                float v = s[ct][r] * 0.125f;
                int q = q0 + hi * 4 + r;
                if (key > q) v = -3.0e38f;
                s[ct][r] = v;
                mt[r] = fmaxf(mt[r], v);
            }
        }
#pragma unroll
        for (int mask = 1; mask < 16; mask <<= 1)
#pragma unroll
            for (int r = 0; r < 4; ++r) mt[r] = fmaxf(mt[r], __shfl_xor(mt[r], mask));
        // ---- online softmax update ----
        float alpha[4], mn[4];
#pragma unroll
        for (int r = 0; r < 4; ++r) {
            mn[r] = fmaxf(m[r], mt[r]);
            alpha[r] = exp2f((m[r] - mn[r]) * L2E);
            m[r] = mn[r];
        }
        float ps[4] = { 0.f, 0.f, 0.f, 0.f };
#pragma unroll
        for (int ct = 0; ct < 4; ++ct) {
#pragma unroll
            for (int r = 0; r < 4; ++r) {
                float p = exp2f((s[ct][r] - mn[r]) * L2E);
                s[ct][r] = p;
                ps[r] += p;
            }
        }
#pragma unroll
        for (int mask = 1; mask < 16; mask <<= 1)
#pragma unroll
            for (int r = 0; r < 4; ++r) ps[r] += __shfl_xor(ps[r], mask);
#pragma unroll
        for (int r = 0; r < 4; ++r) lsum[r] = lsum[r] * alpha[r] + ps[r];
#pragma unroll
        for (int dt = 0; dt < 4; ++dt)
#pragma unroll
            for (int r = 0; r < 4; ++r) o[dt][r] *= alpha[r];
        // ---- P -> bf16 -> per-wave LDS (re-fragment for PV) ----
#pragma unroll
        for (int ct = 0; ct < 4; ++ct)
#pragma unroll
            for (int r = 0; r < 4; ++r)
                Pl[w][hi * 4 + r][lo + 16 * ct] = f2bf(s[ct][r]);
        asm volatile("" ::: "memory");   // keep write->read order; LDS in-order per wave
        bf16x8 pa0 = *(const bf16x8*)&Pl[w][lo][hi * 8];
        bf16x8 pa1 = *(const bf16x8*)&Pl[w][lo][32 + hi * 8];
        // ---- PV ----
#pragma unroll
        for (int dt = 0; dt < 4; ++dt) {
            bf16x8 v0 = *(const bf16x8*)&VbT[(size_t)(lo + 16 * dt) * SEQ + kb + hi * 8];
            bf16x8 v1 = *(const bf16x8*)&VbT[(size_t)(lo + 16 * dt) * SEQ + kb + 32 + hi * 8];
            o[dt] = __builtin_amdgcn_mfma_f32_16x16x32_bf16(pa0, v0, o[dt], 0, 0, 0);
            o[dt] = __builtin_amdgcn_mfma_f32_16x16x32_bf16(pa1, v1, o[dt], 0, 0, 0);
        }
        asm volatile("" ::: "memory");   // Pl reused next iteration
    }

    // ---- stage wave partials in LDS ----
#pragma unroll
    for (int dt = 0; dt < 4; ++dt)
#pragma unroll
        for (int r = 0; r < 4; ++r)
            Osh[w][hi * 4 + r][lo + 16 * dt] = o[dt][r];
    if (lo == 0) {
#pragma unroll
        for (int r = 0; r < 4; ++r) {
            msh[w][hi * 4 + r] = m[r];
            lsh[w][hi * 4 + r] = lsum[r];
        }
    }
    __syncthreads();

    // ---- combine the 8 wave partials (LSE) and write final output ----
    {
        const int q  = tid >> 5;          // 0..15
        const int d0 = (tid & 31) * 2;    // 2 d-elements per thread
        float M = msh[0][q];
#pragma unroll
        for (int ww = 1; ww < 8; ++ww) M = fmaxf(M, msh[ww][q]);
        float L = 0.f, a0 = 0.f, a1 = 0.f;
#pragma unroll
        for (int ww = 0; ww < 8; ++ww) {
            float e = exp2f((msh[ww][q] - M) * L2E);
            L  += e * lsh[ww][q];
            a0 += e * Osh[ww][q][d0];
            a1 += e * Osh[ww][q][d0 + 1];
        }
        float inv = 1.0f / L;
        out[(size_t)(q0 + q) * 64 + d0]     = a0 * inv;
        out[(size_t)(q0 + q) * 64 + d0 + 1] = a1 * inv;
    }
}

// ---------------------------------------------------------------------------
extern "C" void kernel_launch(void* const* d_in, const int* in_sizes, int n_in,
                              void* d_out, int out_size, void* d_ws, size_t ws_size,
                              hipStream_t stream) {
    const float* E  = (const float*)d_in[0];
    const float* Wq = (const float*)d_in[1];
    const float* bq = (const float*)d_in[2];
    const float* Wk = (const float*)d_in[3];
    const float* bk = (const float*)d_in[4];
    const float* Wv = (const float*)d_in[5];
    const float* bv = (const float*)d_in[6];
    float* out = (float*)d_out;

    char* ws = (char*)d_ws;
    unsigned short* Qb  = (unsigned short*)(ws);                    // 512 KB
    unsigned short* Kb  = (unsigned short*)(ws + (512u << 10));     // 512 KB
    unsigned short* VbT = (unsigned short*)(ws + (1024u << 10));    // 512 KB

    hipLaunchKernelGGL(proj_kernel, dim3(SEQ / 16, 3), dim3(256), 0, stream,
                       E, Wq, bq, Wk, bk, Wv, bv, Qb, Kb, VbT);
    hipLaunchKernelGGL(attn_kernel, dim3(SEQ / 16), dim3(512), 0, stream,
                       Qb, Kb, VbT, out);
}

// Round 7
// 110.681 us; speedup vs baseline: 1.1860x; 1.0809x over previous
//
#include <hip/hip_runtime.h>
#include <hip/hip_bf16.h>

#define SEQ 4096
#define DM  512

typedef short bf16x8 __attribute__((ext_vector_type(8)));
typedef short s16x4  __attribute__((ext_vector_type(4)));
typedef float f32x4  __attribute__((ext_vector_type(4)));

#define L2E 1.4426950408889634f
#define EXP2(x) __builtin_amdgcn_exp2f(x)

static __device__ __forceinline__ unsigned short f2bf(float f) {
    unsigned int u = __builtin_bit_cast(unsigned int, f);
    unsigned int r = u + 0x7FFFu + ((u >> 16) & 1u);
    return (unsigned short)(r >> 16);
}

static __device__ __forceinline__ bf16x8 cvt8(const float* __restrict__ p, float s) {
    f32x4 a = *(const f32x4*)p;
    f32x4 b = *(const f32x4*)(p + 4);
    bf16x8 r;
    r[0] = (short)f2bf(a[0] * s); r[1] = (short)f2bf(a[1] * s);
    r[2] = (short)f2bf(a[2] * s); r[3] = (short)f2bf(a[3] * s);
    r[4] = (short)f2bf(b[0] * s); r[5] = (short)f2bf(b[1] * s);
    r[6] = (short)f2bf(b[2] * s); r[7] = (short)f2bf(b[3] * s);
    return r;
}

// ---------------------------------------------------------------------------
// Kernel 0: one-shot f32->bf16 conversion.
//   blocks 0..1023:  E -> Ebf  (2M elems, 8/thread)
//   blocks 1024..1071: Wq|Wk|Wv -> Wbf (Wq pre-scaled by 0.125)
//   block 1072: biases -> bsc f32 (bq pre-scaled by 0.125)
// ---------------------------------------------------------------------------
__global__ __launch_bounds__(256) void cvt_kernel(
    const float* __restrict__ E,
    const float* __restrict__ Wq, const float* __restrict__ bq,
    const float* __restrict__ Wk, const float* __restrict__ bk,
    const float* __restrict__ Wv, const float* __restrict__ bv,
    unsigned short* __restrict__ Ebf, unsigned short* __restrict__ Wbf,
    float* __restrict__ bsc)
{
    const int b = (int)blockIdx.x;
    const int t = (int)threadIdx.x;
    if (b < 1024) {
        size_t off = (size_t)b * 2048 + (size_t)t * 8;
        *(bf16x8*)&Ebf[off] = cvt8(&E[off], 1.0f);
    } else if (b < 1072) {
        int i = b - 1024;                 // 16 blocks per W matrix
        int which = i >> 4;
        const float* W = (which == 0) ? Wq : ((which == 1) ? Wk : Wv);
        float s = (which == 0) ? 0.125f : 1.0f;
        size_t woff = (size_t)(i & 15) * 2048 + (size_t)t * 8;
        *(bf16x8*)&Wbf[(size_t)which * 32768 + woff] = cvt8(&W[woff], s);
    } else {
        if (t < 64)       bsc[t] = bq[t] * 0.125f;
        else if (t < 128) bsc[t] = bk[t - 64];
        else if (t < 192) bsc[t] = bv[t - 128];
    }
}

// ---------------------------------------------------------------------------
// Kernel 1: QKV projection from bf16 inputs, split-K across 4 waves + LDS
//   f32 reduce. grid (SEQ/16, 3), block 256. blockIdx.y: 0=Q,1=K,2=V(transp).
//   Q: [SEQ][64] bf16, PRE-SCALED by 1/8 (Wq,bq scaled upstream).
//   K: [SEQ][64] bf16.  V: VbT[d][n] = V^T, [64][SEQ] bf16.
// ---------------------------------------------------------------------------
__global__ __launch_bounds__(256) void proj_kernel(
    const unsigned short* __restrict__ Ebf,
    const unsigned short* __restrict__ Wbf,
    const float* __restrict__ bsc,
    unsigned short* __restrict__ Qb, unsigned short* __restrict__ Kb,
    unsigned short* __restrict__ VbT)
{
    const int which = blockIdx.y;
    const int bx  = blockIdx.x;
    const int tid = (int)threadIdx.x;
    const int w   = tid >> 6;             // wave 0..3: K-chunk w*128
    const int l   = tid & 63;
    const int lo  = l & 15;
    const int hi  = l >> 4;

    __shared__ float Acc[5120];           // Q/K: [4][16][68]; V: [4][64][20]

    const unsigned short* W = &Wbf[(size_t)which * 32768];
    const float* bias = &bsc[which * 64];

    f32x4 acc[4] = {};

    if (which < 2) {
        unsigned short* out = (which == 0) ? Qb : Kb;
        const int r0 = bx * 16;
#pragma unroll
        for (int kk = 0; kk < 4; ++kk) {
            const int k0 = w * 128 + kk * 32;
            bf16x8 a = *(const bf16x8*)&Ebf[(size_t)(r0 + lo) * DM + k0 + hi * 8];
#pragma unroll
            for (int ct = 0; ct < 4; ++ct) {
                bf16x8 bb = *(const bf16x8*)&W[(size_t)(lo + 16 * ct) * DM + k0 + hi * 8];
                acc[ct] = __builtin_amdgcn_mfma_f32_16x16x32_bf16(a, bb, acc[ct], 0, 0, 0);
            }
        }
#pragma unroll
        for (int ct = 0; ct < 4; ++ct)
#pragma unroll
            for (int r = 0; r < 4; ++r)
                Acc[(w * 16 + hi * 4 + r) * 68 + lo + 16 * ct] = acc[ct][r];
        __syncthreads();
        {
            const int row = tid >> 4;
            const int c0  = (tid & 15) * 4;
            f32x4 sum = {};
#pragma unroll
            for (int ww = 0; ww < 4; ++ww)
                sum += *(const f32x4*)&Acc[(ww * 16 + row) * 68 + c0];
            s16x4 o4;
#pragma unroll
            for (int j = 0; j < 4; ++j)
                o4[j] = (short)f2bf(sum[j] + bias[c0 + j]);
            *(s16x4*)&out[(size_t)(r0 + row) * 64 + c0] = o4;
        }
    } else {
        const int n0 = bx * 16;
#pragma unroll
        for (int kk = 0; kk < 4; ++kk) {
            const int k0 = w * 128 + kk * 32;
            bf16x8 bb = *(const bf16x8*)&Ebf[(size_t)(n0 + lo) * DM + k0 + hi * 8];
#pragma unroll
            for (int ct = 0; ct < 4; ++ct) {
                bf16x8 a = *(const bf16x8*)&W[(size_t)(lo + 16 * ct) * DM + k0 + hi * 8];
                acc[ct] = __builtin_amdgcn_mfma_f32_16x16x32_bf16(a, bb, acc[ct], 0, 0, 0);
            }
        }
#pragma unroll
        for (int ct = 0; ct < 4; ++ct)
#pragma unroll
            for (int r = 0; r < 4; ++r)
                Acc[(w * 64 + 16 * ct + hi * 4 + r) * 20 + lo] = acc[ct][r];
        __syncthreads();
        {
            const int d  = tid >> 2;
            const int n4 = (tid & 3) * 4;
            f32x4 sum = {};
#pragma unroll
            for (int ww = 0; ww < 4; ++ww)
                sum += *(const f32x4*)&Acc[(ww * 64 + d) * 20 + n4];
            const float bd = bias[d];
            s16x4 o4;
#pragma unroll
            for (int j = 0; j < 4; ++j)
                o4[j] = (short)f2bf(sum[j] + bd);
            *(s16x4*)&VbT[(size_t)d * SEQ + n0 + n4] = o4;
        }
    }
}

// ---------------------------------------------------------------------------
// Kernel 2: causal flash attention, single pass, 8 waves per block.
//   grid (SEQ/16), block 512. Wave w takes k-blocks w, w+8, ...
//   Q pre-scaled => no per-element scale. Exactly ONE partially-masked
//   k-block per q-tile (kb <= q0 always; masked iff kb+63 > q0) => the
//   mask path is a wave-uniform branch taken once.
// ---------------------------------------------------------------------------
__global__ __launch_bounds__(512) void attn_kernel(
    const unsigned short* __restrict__ Qb,
    const unsigned short* __restrict__ Kb,
    const unsigned short* __restrict__ VbT,
    float* __restrict__ out)
{
    const int q0  = blockIdx.x * 16;
    const int tid = (int)threadIdx.x;
    const int w   = tid >> 6;
    const int l   = tid & 63;
    const int lo  = l & 15;
    const int hi  = l >> 4;

    __shared__ unsigned short Pl[8][16][80];
    __shared__ float Osh[8][16][64];
    __shared__ float msh[8][16];
    __shared__ float lsh[8][16];

    bf16x8 qf0 = *(const bf16x8*)&Qb[(size_t)(q0 + lo) * 64 + hi * 8];
    bf16x8 qf1 = *(const bf16x8*)&Qb[(size_t)(q0 + lo) * 64 + 32 + hi * 8];

    float m[4], lsum[4];
    f32x4 o[4] = {};
#pragma unroll
    for (int r = 0; r < 4; ++r) { m[r] = -1e30f; lsum[r] = 0.f; }

    const int kend = q0 + 16;
    for (int kb = w * 64; kb < kend; kb += 512) {
        // ---- QK^T (16 q x 64 k) ----
        f32x4 s[4] = {};
#pragma unroll
        for (int ct = 0; ct < 4; ++ct) {
            bf16x8 kf0 = *(const bf16x8*)&Kb[(size_t)(kb + lo + 16 * ct) * 64 + hi * 8];
            bf16x8 kf1 = *(const bf16x8*)&Kb[(size_t)(kb + lo + 16 * ct) * 64 + 32 + hi * 8];
            s[ct] = __builtin_amdgcn_mfma_f32_16x16x32_bf16(qf0, kf0, s[ct], 0, 0, 0);
            s[ct] = __builtin_amdgcn_mfma_f32_16x16x32_bf16(qf1, kf1, s[ct], 0, 0, 0);
        }
        // ---- causal mask (one block per tile) + row max ----
        float mt[4] = { -1e30f, -1e30f, -1e30f, -1e30f };
        if (kb + 63 > q0) {
#pragma unroll
            for (int ct = 0; ct < 4; ++ct) {
                int key = kb + lo + 16 * ct;
#pragma unroll
                for (int r = 0; r < 4; ++r) {
                    float v = s[ct][r];
                    if (key > q0 + hi * 4 + r) v = -3.0e38f;
                    s[ct][r] = v;
                    mt[r] = fmaxf(mt[r], v);
                }
            }
        } else {
#pragma unroll
            for (int ct = 0; ct < 4; ++ct)
#pragma unroll
                for (int r = 0; r < 4; ++r) mt[r] = fmaxf(mt[r], s[ct][r]);
        }
#pragma unroll
        for (int mask = 1; mask < 16; mask <<= 1)
#pragma unroll
            for (int r = 0; r < 4; ++r) mt[r] = fmaxf(mt[r], __shfl_xor(mt[r], mask));
        // ---- online softmax update ----
        float alpha[4], mn[4];
#pragma unroll
        for (int r = 0; r < 4; ++r) {
            mn[r] = fmaxf(m[r], mt[r]);
            alpha[r] = EXP2((m[r] - mn[r]) * L2E);
            m[r] = mn[r];
        }
        float ps[4] = { 0.f, 0.f, 0.f, 0.f };
#pragma unroll
        for (int ct = 0; ct < 4; ++ct) {
#pragma unroll
            for (int r = 0; r < 4; ++r) {
                float p = EXP2((s[ct][r] - mn[r]) * L2E);
                s[ct][r] = p;
                ps[r] += p;
            }
        }
#pragma unroll
        for (int mask = 1; mask < 16; mask <<= 1)
#pragma unroll
            for (int r = 0; r < 4; ++r) ps[r] += __shfl_xor(ps[r], mask);
#pragma unroll
        for (int r = 0; r < 4; ++r) lsum[r] = lsum[r] * alpha[r] + ps[r];
#pragma unroll
        for (int dt = 0; dt < 4; ++dt)
#pragma unroll
            for (int r = 0; r < 4; ++r) o[dt][r] *= alpha[r];
        // ---- P -> bf16 -> per-wave LDS (re-fragment for PV) ----
#pragma unroll
        for (int ct = 0; ct < 4; ++ct)
#pragma unroll
            for (int r = 0; r < 4; ++r)
                Pl[w][hi * 4 + r][lo + 16 * ct] = f2bf(s[ct][r]);
        asm volatile("" ::: "memory");
        bf16x8 pa0 = *(const bf16x8*)&Pl[w][lo][hi * 8];
        bf16x8 pa1 = *(const bf16x8*)&Pl[w][lo][32 + hi * 8];
        // ---- PV ----
#pragma unroll
        for (int dt = 0; dt < 4; ++dt) {
            bf16x8 v0 = *(const bf16x8*)&VbT[(size_t)(lo + 16 * dt) * SEQ + kb + hi * 8];
            bf16x8 v1 = *(const bf16x8*)&VbT[(size_t)(lo + 16 * dt) * SEQ + kb + 32 + hi * 8];
            o[dt] = __builtin_amdgcn_mfma_f32_16x16x32_bf16(pa0, v0, o[dt], 0, 0, 0);
            o[dt] = __builtin_amdgcn_mfma_f32_16x16x32_bf16(pa1, v1, o[dt], 0, 0, 0);
        }
        asm volatile("" ::: "memory");
    }

    // ---- stage wave partials in LDS ----
#pragma unroll
    for (int dt = 0; dt < 4; ++dt)
#pragma unroll
        for (int r = 0; r < 4; ++r)
            Osh[w][hi * 4 + r][lo + 16 * dt] = o[dt][r];
    if (lo == 0) {
#pragma unroll
        for (int r = 0; r < 4; ++r) {
            msh[w][hi * 4 + r] = m[r];
            lsh[w][hi * 4 + r] = lsum[r];
        }
    }
    __syncthreads();

    // ---- combine the 8 wave partials (LSE), write normalized output ----
    {
        const int q  = tid >> 5;
        const int d0 = (tid & 31) * 2;
        float M = msh[0][q];
#pragma unroll
        for (int ww = 1; ww < 8; ++ww) M = fmaxf(M, msh[ww][q]);
        float L = 0.f, a0 = 0.f, a1 = 0.f;
#pragma unroll
        for (int ww = 0; ww < 8; ++ww) {
            float e = EXP2((msh[ww][q] - M) * L2E);
            L  += e * lsh[ww][q];
            a0 += e * Osh[ww][q][d0];
            a1 += e * Osh[ww][q][d0 + 1];
        }
        float inv = 1.0f / L;
        out[(size_t)(q0 + q) * 64 + d0]     = a0 * inv;
        out[(size_t)(q0 + q) * 64 + d0 + 1] = a1 * inv;
    }
}

// ---------------------------------------------------------------------------
extern "C" void kernel_launch(void* const* d_in, const int* in_sizes, int n_in,
                              void* d_out, int out_size, void* d_ws, size_t ws_size,
                              hipStream_t stream) {
    const float* E  = (const float*)d_in[0];
    const float* Wq = (const float*)d_in[1];
    const float* bq = (const float*)d_in[2];
    const float* Wk = (const float*)d_in[3];
    const float* bk = (const float*)d_in[4];
    const float* Wv = (const float*)d_in[5];
    const float* bv = (const float*)d_in[6];
    float* out = (float*)d_out;

    char* ws = (char*)d_ws;
    unsigned short* Qb  = (unsigned short*)(ws);                    // 512 KB
    unsigned short* Kb  = (unsigned short*)(ws + (512u << 10));     // 512 KB
    unsigned short* VbT = (unsigned short*)(ws + (1024u << 10));    // 512 KB
    unsigned short* Ebf = (unsigned short*)(ws + (1536u << 10));    // 4 MB
    unsigned short* Wbf = (unsigned short*)(ws + (5632u << 10));    // 192 KB
    float*          bsc = (float*)(ws + (5888u << 10));             // 768 B

    hipLaunchKernelGGL(cvt_kernel, dim3(1073), dim3(256), 0, stream,
                       E, Wq, bq, Wk, bk, Wv, bv, Ebf, Wbf, bsc);
    hipLaunchKernelGGL(proj_kernel, dim3(SEQ / 16, 3), dim3(256), 0, stream,
                       Ebf, Wbf, bsc, Qb, Kb, VbT);
    hipLaunchKernelGGL(attn_kernel, dim3(SEQ / 16), dim3(512), 0, stream,
                       Qb, Kb, VbT, out);
}